// Round 1
// baseline (453.459 us; speedup 1.0000x reference)
//
#include <hip/hip_runtime.h>
#include <hip/hip_bf16.h>
#include <stdint.h>

#define D_MODEL 1024
#define NUM_EXPERTS 8
#define BM 128
#define BN 128
#define BK 64

typedef __bf16 bf16x8 __attribute__((ext_vector_type(8)));
typedef float f32x4 __attribute__((ext_vector_type(4)));

__device__ __forceinline__ unsigned short f32_to_bf16_rne(float f) {
    union { float f; uint32_t u; } v;
    v.f = f;
    uint32_t u = v.u;
    u += 0x7FFFu + ((u >> 16) & 1u);   // round-to-nearest-even
    return (unsigned short)(u >> 16);
}

__device__ __forceinline__ void gload_lds16(const unsigned short* g, unsigned short* l) {
    __builtin_amdgcn_global_load_lds(
        (const __attribute__((address_space(1))) void*)g,
        (__attribute__((address_space(3))) void*)l,
        16, 0, 0);
}

// ---------------------------------------------------------------------------
// Gate kernel: one wave per token. fp64-accumulated logits -> softmax -> top-2
// (strict >, lower index wins ties, matching lax.top_k / numpy). Appends the
// token to its two expert buckets via atomics, and converts the token's x row
// to bf16 (fused, saves a separate pass over x).
// ---------------------------------------------------------------------------
__global__ __launch_bounds__(64) void gate_kernel(
    const float* __restrict__ x, const float* __restrict__ Wg,
    const float* __restrict__ bg, int T,
    int* __restrict__ counts, int* __restrict__ token_list,
    float* __restrict__ gate_list, unsigned short* __restrict__ xb)
{
    const int token = blockIdx.x;
    const int lane  = threadIdx.x;
    const float* xr = x + (size_t)token * D_MODEL;

    float xv[16];
#pragma unroll
    for (int j = 0; j < 16; j++) xv[j] = xr[lane + j * 64];

    // fused fp32->bf16 conversion of this token's row
    unsigned short* xbr = xb + (size_t)token * D_MODEL;
#pragma unroll
    for (int j = 0; j < 16; j++) xbr[lane + j * 64] = f32_to_bf16_rne(xv[j]);

    double acc[NUM_EXPERTS];
#pragma unroll
    for (int e = 0; e < NUM_EXPERTS; e++) {
        const float* wr = Wg + e * D_MODEL;
        double a = 0.0;
#pragma unroll
        for (int j = 0; j < 16; j++) a += (double)xv[j] * (double)wr[lane + j * 64];
        acc[e] = a;
    }
    // butterfly reduce across the wave
#pragma unroll
    for (int e = 0; e < NUM_EXPERTS; e++) {
        double a = acc[e];
        for (int off = 32; off > 0; off >>= 1) a += __shfl_xor(a, off, 64);
        acc[e] = a;
    }
    if (lane == 0) {
        double logit[NUM_EXPERTS];
        for (int e = 0; e < NUM_EXPERTS; e++) logit[e] = acc[e] + (double)bg[e];
        int i1 = 0;
        for (int e = 1; e < NUM_EXPERTS; e++) if (logit[e] > logit[i1]) i1 = e;
        int i2 = (i1 == 0) ? 1 : 0;
        for (int e = 0; e < NUM_EXPERTS; e++)
            if (e != i1 && logit[e] > logit[i2]) i2 = e;
        double m = logit[i1];
        double denom = 0.0;
        for (int e = 0; e < NUM_EXPERTS; e++) denom += exp(logit[e] - m);
        float v1 = (float)(exp(logit[i1] - m) / denom);
        float v2 = (float)(exp(logit[i2] - m) / denom);
        int s1 = atomicAdd(&counts[i1], 1);
        token_list[i1 * T + s1] = token;
        gate_list[i1 * T + s1]  = v1;
        int s2 = atomicAdd(&counts[i2], 1);
        token_list[i2 * T + s2] = token;
        gate_list[i2 * T + s2]  = v2;
    }
}

// ---------------------------------------------------------------------------
// fp32 -> bf16 converter (for We), float4-vectorized
// ---------------------------------------------------------------------------
__global__ __launch_bounds__(256) void convert_kernel(
    const float* __restrict__ src, unsigned short* __restrict__ dst, int n4)
{
    int i = blockIdx.x * 256 + threadIdx.x;
    if (i >= n4) return;
    float4 f = ((const float4*)src)[i];
    ushort4 o;
    o.x = f32_to_bf16_rne(f.x);
    o.y = f32_to_bf16_rne(f.y);
    o.z = f32_to_bf16_rne(f.z);
    o.w = f32_to_bf16_rne(f.w);
    ((ushort4*)dst)[i] = o;
}

// ---------------------------------------------------------------------------
// Per-expert gathered GEMM: C[m,n] = sum_k xb[tok[m],k] * We_bf16[e][n][k]
// m97 structure: 128x128 tile, BK=64, global_load_lds(16B) staging,
// 16x16x32 bf16 MFMA, 2x2 wave grid, 4x4 frag tiles per wave.
// Epilogue: atomicAdd(out[tok, n], gate * (acc + be[e,n])).
// ---------------------------------------------------------------------------
__global__ __launch_bounds__(256) void moe_gemm(
    const unsigned short* __restrict__ xb,   // [T][1024] bf16
    const unsigned short* __restrict__ wb,   // [E][1024][1024] bf16, K-contig
    const float* __restrict__ be,            // [E][1024]
    const int* __restrict__ counts,
    const int* __restrict__ token_list,      // [E][T]
    const float* __restrict__ gate_list,     // [E][T]
    float* __restrict__ out, int T)
{
    const int bid = blockIdx.x;
    const int nt = bid & 7;          // 8 n-tiles (1024/128), fastest for A reuse
    const int rest = bid >> 3;
    const int e  = rest & (NUM_EXPERTS - 1);
    const int mt = rest >> 3;

    const int n_e = counts[e];
    const int m0 = mt * BM;
    if (m0 >= n_e) return;
    const int n0 = nt * BN;
    const int tid = threadIdx.x;

    __shared__ __align__(16) unsigned short As[BM * BK];
    __shared__ __align__(16) unsigned short Bs[BN * BK];
    __shared__ int   tokS[BM];
    __shared__ float gateS[BM];

    if (tid < BM) {
        int r = m0 + tid;
        int tk = 0; float gv = 0.f;
        if (r < n_e) {
            tk = token_list[e * T + r];
            gv = gate_list[e * T + r];
        }
        tokS[tid]  = tk;
        gateS[tid] = gv;
    }
    __syncthreads();

    // Precompute per-thread staging source rows (fixed across K-loop).
    // flat = i*256 + tid in [0,1024): row = flat>>3, 16B-segment = flat&7.
    const unsigned short* asrc[4];
    const unsigned short* bsrc[4];
    const unsigned short* wbase = wb + (size_t)e * D_MODEL * D_MODEL;
#pragma unroll
    for (int i = 0; i < 4; i++) {
        int flat = i * 256 + tid;
        int r = flat >> 3, seg = flat & 7;
        asrc[i] = xb + (size_t)tokS[r] * D_MODEL + seg * 8;
        bsrc[i] = wbase + (size_t)(n0 + r) * D_MODEL + seg * 8;
    }

    const int wave = tid >> 6, lane = tid & 63;
    const int wm = (wave >> 1) * 64, wn = (wave & 1) * 64;
    const int frow = lane & 15;
    const int fk = (lane >> 4) * 8;

    f32x4 acc[4][4];
#pragma unroll
    for (int mi = 0; mi < 4; mi++)
#pragma unroll
        for (int ni = 0; ni < 4; ni++)
            acc[mi][ni] = (f32x4){0.f, 0.f, 0.f, 0.f};

    for (int kt = 0; kt < D_MODEL / BK; kt++) {
        const int k0 = kt * BK;
#pragma unroll
        for (int i = 0; i < 4; i++) {
            int flat = i * 256 + tid;
            gload_lds16(asrc[i] + k0, &As[flat * 8]);
            gload_lds16(bsrc[i] + k0, &Bs[flat * 8]);
        }
        __syncthreads();
#pragma unroll
        for (int ks = 0; ks < 2; ks++) {
            bf16x8 af[4], bfv[4];
#pragma unroll
            for (int mi = 0; mi < 4; mi++)
                af[mi] = *(const bf16x8*)&As[(wm + mi * 16 + frow) * BK + ks * 32 + fk];
#pragma unroll
            for (int ni = 0; ni < 4; ni++)
                bfv[ni] = *(const bf16x8*)&Bs[(wn + ni * 16 + frow) * BK + ks * 32 + fk];
#pragma unroll
            for (int mi = 0; mi < 4; mi++)
#pragma unroll
                for (int ni = 0; ni < 4; ni++)
                    acc[mi][ni] = __builtin_amdgcn_mfma_f32_16x16x32_bf16(
                        af[mi], bfv[ni], acc[mi][ni], 0, 0, 0);
        }
        __syncthreads();
    }

    // Epilogue: C/D layout col = lane&15, row = (lane>>4)*4 + reg
    const int rbase = (lane >> 4) * 4;
    const int col   = lane & 15;
#pragma unroll
    for (int mi = 0; mi < 4; mi++) {
#pragma unroll
        for (int r = 0; r < 4; r++) {
            int lrow = wm + mi * 16 + rbase + r;
            if (m0 + lrow < n_e) {
                int   tk = tokS[lrow];
                float gv = gateS[lrow];
#pragma unroll
                for (int ni = 0; ni < 4; ni++) {
                    int c = n0 + wn + ni * 16 + col;
                    float val = gv * (acc[mi][ni][r] + be[e * D_MODEL + c]);
                    atomicAdd(&out[(size_t)tk * D_MODEL + c], val);
                }
            }
        }
    }
}

extern "C" void kernel_launch(void* const* d_in, const int* in_sizes, int n_in,
                              void* d_out, int out_size, void* d_ws, size_t ws_size,
                              hipStream_t stream) {
    const float* x  = (const float*)d_in[0];
    const float* Wg = (const float*)d_in[1];
    const float* bg = (const float*)d_in[2];
    const float* We = (const float*)d_in[3];
    const float* be = (const float*)d_in[4];
    // top_k (d_in[5]) is fixed at 2 per the reference; hard-coded.

    const int T = in_sizes[0] / D_MODEL;   // 8192 tokens

    // workspace carve-up
    char* ws = (char*)d_ws;
    unsigned short* xb = (unsigned short*)ws;                       // T*D bf16
    size_t off = (size_t)T * D_MODEL * 2;
    unsigned short* wbv = (unsigned short*)(ws + off);              // E*D*D bf16
    off += (size_t)NUM_EXPERTS * D_MODEL * D_MODEL * 2;
    int* counts = (int*)(ws + off);         off += 256;
    int* token_list = (int*)(ws + off);     off += (size_t)NUM_EXPERTS * T * 4;
    float* gate_list = (float*)(ws + off);  off += (size_t)NUM_EXPERTS * T * 4;

    hipMemsetAsync(counts, 0, 256, stream);
    hipMemsetAsync(d_out, 0, (size_t)out_size * sizeof(float), stream);

    int n4w = NUM_EXPERTS * D_MODEL * D_MODEL / 4;
    convert_kernel<<<(n4w + 255) / 256, 256, 0, stream>>>(We, wbv, n4w);

    gate_kernel<<<T, 64, 0, stream>>>(x, Wg, bg, T, counts, token_list, gate_list, xb);

    const int MT = (T + BM - 1) / BM;       // worst case: all tokens on one expert
    moe_gemm<<<MT * NUM_EXPERTS * 8, 256, 0, stream>>>(
        xb, wbv, be, counts, token_list, gate_list, (float*)d_out, T);
}

// Round 2
// 291.249 us; speedup vs baseline: 1.5569x; 1.5569x over previous
//
#include <hip/hip_runtime.h>
#include <hip/hip_bf16.h>
#include <stdint.h>

#define D_MODEL 1024
#define NUM_EXPERTS 8
#define BM 128
#define BN 128
#define BK 64
#define GATE_TOK 32   // tokens per gate block

typedef __bf16 bf16x8 __attribute__((ext_vector_type(8)));
typedef float f32x4 __attribute__((ext_vector_type(4)));

__device__ __forceinline__ unsigned short f32_to_bf16_rne(float f) {
    union { float f; uint32_t u; } v;
    v.f = f;
    uint32_t u = v.u;
    u += 0x7FFFu + ((u >> 16) & 1u);   // round-to-nearest-even
    return (unsigned short)(u >> 16);
}

__device__ __forceinline__ void gload_lds16(const unsigned short* g, unsigned short* l) {
    __builtin_amdgcn_global_load_lds(
        (const __attribute__((address_space(1))) void*)g,
        (__attribute__((address_space(3))) void*)l,
        16, 0, 0);
}

// ---------------------------------------------------------------------------
// Gate kernel v2: 256 threads / 32 tokens per block (8 tokens per wave).
// fp64-accumulated logits (selection-exact vs numpy, same as the passing R1
// version), fp64 softmax, strict-> top-2 with lower-index tie-break.
// Bucket append is BLOCK-AGGREGATED: LDS histogram -> one 8-lane vector
// atomic per block to reserve ranges -> conflict-free scatter. This removes
// the 16384 serialized same-line returning atomics that cost 200 us in R1.
// Also fuses x fp32->bf16 conversion (RNE).
// ---------------------------------------------------------------------------
__global__ __launch_bounds__(256) void gate_kernel(
    const float* __restrict__ x, const float* __restrict__ Wg,
    const float* __restrict__ bg, int T,
    int* __restrict__ counts, int* __restrict__ token_list,
    float* __restrict__ gate_list, unsigned short* __restrict__ xb)
{
    const int tid  = threadIdx.x;
    const int lane = tid & 63;
    const int wave = tid >> 6;
    const int tokBase = blockIdx.x * GATE_TOK;

    __shared__ double logitS[GATE_TOK][NUM_EXPERTS];
    __shared__ int cntS[NUM_EXPERTS];
    __shared__ int baseS[NUM_EXPERTS];
    if (tid < NUM_EXPERTS) cntS[tid] = 0;

    // Preload this lane's Wg fragment (16 columns per expert), reused for all
    // 8 tokens of this wave. Columns: k = q*256 + lane*4 + j.
    float wgr[NUM_EXPERTS][16];
#pragma unroll
    for (int e = 0; e < NUM_EXPERTS; e++) {
        const float4* w4p = (const float4*)(Wg + e * D_MODEL);
#pragma unroll
        for (int q = 0; q < 4; q++) {
            float4 w4 = w4p[q * 64 + lane];
            wgr[e][q * 4 + 0] = w4.x;
            wgr[e][q * 4 + 1] = w4.y;
            wgr[e][q * 4 + 2] = w4.z;
            wgr[e][q * 4 + 3] = w4.w;
        }
    }

    // Each wave handles 8 tokens.
#pragma unroll 2
    for (int tt = 0; tt < GATE_TOK / 4; tt++) {
        const int lt = wave * (GATE_TOK / 4) + tt;
        const int token = tokBase + lt;
        const float4* xr4 = (const float4*)(x + (size_t)token * D_MODEL);
        ushort4* xbr4 = (ushort4*)(xb + (size_t)token * D_MODEL);

        float xv[16];
#pragma unroll
        for (int q = 0; q < 4; q++) {
            float4 f = xr4[q * 64 + lane];
            xv[q * 4 + 0] = f.x;
            xv[q * 4 + 1] = f.y;
            xv[q * 4 + 2] = f.z;
            xv[q * 4 + 3] = f.w;
            ushort4 o;
            o.x = f32_to_bf16_rne(f.x);
            o.y = f32_to_bf16_rne(f.y);
            o.z = f32_to_bf16_rne(f.z);
            o.w = f32_to_bf16_rne(f.w);
            xbr4[q * 64 + lane] = o;
        }

        double acc[NUM_EXPERTS];
#pragma unroll
        for (int e = 0; e < NUM_EXPERTS; e++) {
            double a = 0.0;
#pragma unroll
            for (int i = 0; i < 16; i++) a += (double)xv[i] * (double)wgr[e][i];
            acc[e] = a;
        }
#pragma unroll
        for (int e = 0; e < NUM_EXPERTS; e++) {
            double a = acc[e];
            for (int off = 32; off > 0; off >>= 1) a += __shfl_xor(a, off, 64);
            acc[e] = a;
        }
        if (lane == 0) {
#pragma unroll
            for (int e = 0; e < NUM_EXPERTS; e++)
                logitS[lt][e] = acc[e] + (double)bg[e];
        }
    }
    __syncthreads();

    // Phase 2: one thread per token — top-2 + softmax + LDS-aggregated append.
    int i1 = 0, i2 = 0, o1 = 0, o2 = 0;
    double v1d = 0.0, v2d = 0.0;
    const int token2 = tokBase + tid;
    if (tid < GATE_TOK) {
        double lg[NUM_EXPERTS];
#pragma unroll
        for (int e = 0; e < NUM_EXPERTS; e++) lg[e] = logitS[tid][e];
        i1 = 0;
#pragma unroll
        for (int e = 1; e < NUM_EXPERTS; e++) if (lg[e] > lg[i1]) i1 = e;
        i2 = (i1 == 0) ? 1 : 0;
#pragma unroll
        for (int e = 0; e < NUM_EXPERTS; e++)
            if (e != i1 && lg[e] > lg[i2]) i2 = e;
        double m = lg[i1], den = 0.0;
#pragma unroll
        for (int e = 0; e < NUM_EXPERTS; e++) den += exp(lg[e] - m);
        v1d = exp(lg[i1] - m) / den;
        v2d = exp(lg[i2] - m) / den;
        o1 = atomicAdd(&cntS[i1], 1);
        o2 = atomicAdd(&cntS[i2], 1);
    }
    __syncthreads();
    if (tid < NUM_EXPERTS) baseS[tid] = atomicAdd(&counts[tid], cntS[tid]);
    __syncthreads();
    if (tid < GATE_TOK) {
        int p1 = i1 * T + baseS[i1] + o1;
        token_list[p1] = token2;
        gate_list[p1]  = (float)v1d;
        int p2 = i2 * T + baseS[i2] + o2;
        token_list[p2] = token2;
        gate_list[p2]  = (float)v2d;
    }
}

// ---------------------------------------------------------------------------
// fp32 -> bf16 converter (for We), float4-vectorized
// ---------------------------------------------------------------------------
__global__ __launch_bounds__(256) void convert_kernel(
    const float* __restrict__ src, unsigned short* __restrict__ dst, int n4)
{
    int i = blockIdx.x * 256 + threadIdx.x;
    if (i >= n4) return;
    float4 f = ((const float4*)src)[i];
    ushort4 o;
    o.x = f32_to_bf16_rne(f.x);
    o.y = f32_to_bf16_rne(f.y);
    o.z = f32_to_bf16_rne(f.z);
    o.w = f32_to_bf16_rne(f.w);
    ((ushort4*)dst)[i] = o;
}

// ---------------------------------------------------------------------------
// Per-expert gathered GEMM: C[m,n] = sum_k xb[tok[m],k] * We_bf16[e][n][k]
// m97 structure: 128x128 tile, BK=64, global_load_lds(16B) staging,
// 16x16x32 bf16 MFMA, 2x2 wave grid, 4x4 frag tiles per wave.
// Epilogue: atomicAdd(out[tok, n], gate * (acc + be[e,n])).
// ---------------------------------------------------------------------------
__global__ __launch_bounds__(256) void moe_gemm(
    const unsigned short* __restrict__ xb,   // [T][1024] bf16
    const unsigned short* __restrict__ wb,   // [E][1024][1024] bf16, K-contig
    const float* __restrict__ be,            // [E][1024]
    const int* __restrict__ counts,
    const int* __restrict__ token_list,      // [E][T]
    const float* __restrict__ gate_list,     // [E][T]
    float* __restrict__ out, int T)
{
    const int bid = blockIdx.x;
    const int nt = bid & 7;          // 8 n-tiles (1024/128), fastest for A reuse
    const int rest = bid >> 3;
    const int e  = rest & (NUM_EXPERTS - 1);
    const int mt = rest >> 3;

    const int n_e = counts[e];
    const int m0 = mt * BM;
    if (m0 >= n_e) return;
    const int n0 = nt * BN;
    const int tid = threadIdx.x;

    __shared__ __align__(16) unsigned short As[BM * BK];
    __shared__ __align__(16) unsigned short Bs[BN * BK];
    __shared__ int   tokS[BM];
    __shared__ float gateS[BM];

    if (tid < BM) {
        int r = m0 + tid;
        int tk = 0; float gv = 0.f;
        if (r < n_e) {
            tk = token_list[e * T + r];
            gv = gate_list[e * T + r];
        }
        tokS[tid]  = tk;
        gateS[tid] = gv;
    }
    __syncthreads();

    // Precompute per-thread staging source rows (fixed across K-loop).
    // flat = i*256 + tid in [0,1024): row = flat>>3, 16B-segment = flat&7.
    const unsigned short* asrc[4];
    const unsigned short* bsrc[4];
    const unsigned short* wbase = wb + (size_t)e * D_MODEL * D_MODEL;
#pragma unroll
    for (int i = 0; i < 4; i++) {
        int flat = i * 256 + tid;
        int r = flat >> 3, seg = flat & 7;
        asrc[i] = xb + (size_t)tokS[r] * D_MODEL + seg * 8;
        bsrc[i] = wbase + (size_t)(n0 + r) * D_MODEL + seg * 8;
    }

    const int wave = tid >> 6, lane = tid & 63;
    const int wm = (wave >> 1) * 64, wn = (wave & 1) * 64;
    const int frow = lane & 15;
    const int fk = (lane >> 4) * 8;

    f32x4 acc[4][4];
#pragma unroll
    for (int mi = 0; mi < 4; mi++)
#pragma unroll
        for (int ni = 0; ni < 4; ni++)
            acc[mi][ni] = (f32x4){0.f, 0.f, 0.f, 0.f};

    for (int kt = 0; kt < D_MODEL / BK; kt++) {
        const int k0 = kt * BK;
#pragma unroll
        for (int i = 0; i < 4; i++) {
            int flat = i * 256 + tid;
            gload_lds16(asrc[i] + k0, &As[flat * 8]);
            gload_lds16(bsrc[i] + k0, &Bs[flat * 8]);
        }
        __syncthreads();
#pragma unroll
        for (int ks = 0; ks < 2; ks++) {
            bf16x8 af[4], bfv[4];
#pragma unroll
            for (int mi = 0; mi < 4; mi++)
                af[mi] = *(const bf16x8*)&As[(wm + mi * 16 + frow) * BK + ks * 32 + fk];
#pragma unroll
            for (int ni = 0; ni < 4; ni++)
                bfv[ni] = *(const bf16x8*)&Bs[(wn + ni * 16 + frow) * BK + ks * 32 + fk];
#pragma unroll
            for (int mi = 0; mi < 4; mi++)
#pragma unroll
                for (int ni = 0; ni < 4; ni++)
                    acc[mi][ni] = __builtin_amdgcn_mfma_f32_16x16x32_bf16(
                        af[mi], bfv[ni], acc[mi][ni], 0, 0, 0);
        }
        __syncthreads();
    }

    // Epilogue: C/D layout col = lane&15, row = (lane>>4)*4 + reg
    const int rbase = (lane >> 4) * 4;
    const int col   = lane & 15;
#pragma unroll
    for (int mi = 0; mi < 4; mi++) {
#pragma unroll
        for (int r = 0; r < 4; r++) {
            int lrow = wm + mi * 16 + rbase + r;
            if (m0 + lrow < n_e) {
                int   tk = tokS[lrow];
                float gv = gateS[lrow];
#pragma unroll
                for (int ni = 0; ni < 4; ni++) {
                    int c = n0 + wn + ni * 16 + col;
                    float val = gv * (acc[mi][ni][r] + be[e * D_MODEL + c]);
                    atomicAdd(&out[(size_t)tk * D_MODEL + c], val);
                }
            }
        }
    }
}

extern "C" void kernel_launch(void* const* d_in, const int* in_sizes, int n_in,
                              void* d_out, int out_size, void* d_ws, size_t ws_size,
                              hipStream_t stream) {
    const float* x  = (const float*)d_in[0];
    const float* Wg = (const float*)d_in[1];
    const float* bg = (const float*)d_in[2];
    const float* We = (const float*)d_in[3];
    const float* be = (const float*)d_in[4];
    // top_k (d_in[5]) is fixed at 2 per the reference; hard-coded.

    const int T = in_sizes[0] / D_MODEL;   // 8192 tokens

    // workspace carve-up
    char* ws = (char*)d_ws;
    unsigned short* xb = (unsigned short*)ws;                       // T*D bf16
    size_t off = (size_t)T * D_MODEL * 2;
    unsigned short* wbv = (unsigned short*)(ws + off);              // E*D*D bf16
    off += (size_t)NUM_EXPERTS * D_MODEL * D_MODEL * 2;
    int* counts = (int*)(ws + off);         off += 256;
    int* token_list = (int*)(ws + off);     off += (size_t)NUM_EXPERTS * T * 4;
    float* gate_list = (float*)(ws + off);  off += (size_t)NUM_EXPERTS * T * 4;

    hipMemsetAsync(counts, 0, 256, stream);
    hipMemsetAsync(d_out, 0, (size_t)out_size * sizeof(float), stream);

    int n4w = NUM_EXPERTS * D_MODEL * D_MODEL / 4;
    convert_kernel<<<(n4w + 255) / 256, 256, 0, stream>>>(We, wbv, n4w);

    gate_kernel<<<T / GATE_TOK, 256, 0, stream>>>(
        x, Wg, bg, T, counts, token_list, gate_list, xb);

    const int MT = (T + BM - 1) / BM;       // worst case: all tokens on one expert
    moe_gemm<<<MT * NUM_EXPERTS * 8, 256, 0, stream>>>(
        xb, wbv, be, counts, token_list, gate_list, (float*)d_out, T);
}

// Round 3
// 215.790 us; speedup vs baseline: 2.1014x; 1.3497x over previous
//
#include <hip/hip_runtime.h>
#include <hip/hip_bf16.h>
#include <stdint.h>

#define D_MODEL 1024
#define NUM_EXPERTS 8
#define NBUCKET 16            // 8 primary + 8 secondary virtual experts
#define BM 128
#define BN 128
#define BK 64
#define GATE_TOK 32           // tokens per gate block

typedef __bf16 bf16x8 __attribute__((ext_vector_type(8)));
typedef float f32x4 __attribute__((ext_vector_type(4)));

__device__ __forceinline__ unsigned short f32_to_bf16_rne(float f) {
    union { float f; uint32_t u; } v;
    v.f = f;
    uint32_t u = v.u;
    u += 0x7FFFu + ((u >> 16) & 1u);   // round-to-nearest-even
    return (unsigned short)(u >> 16);
}

__device__ __forceinline__ float bf16_to_f32(unsigned short h) {
    union { uint32_t u; float f; } v;
    v.u = ((uint32_t)h) << 16;
    return v.f;
}

__device__ __forceinline__ void gload_lds16(const unsigned short* g, unsigned short* l) {
    __builtin_amdgcn_global_load_lds(
        (const __attribute__((address_space(1))) void*)g,
        (__attribute__((address_space(3))) void*)l,
        16, 0, 0);
}

// ---------------------------------------------------------------------------
// Gate kernel v3: Wg staged in LDS (v2's 128-VGPR register preload spilled).
// fp64 logits -> strict-> top-2 (lower index wins ties, matches lax.top_k),
// fp64 softmax. 16 buckets: primary expert -> bucket e, secondary -> 8+e.
// Block-aggregated bucket append (one 16-lane atomic volley per block).
// Fuses x fp32->bf16 (RNE) conversion.
// ---------------------------------------------------------------------------
__global__ __launch_bounds__(256) void gate_kernel(
    const float* __restrict__ x, const float* __restrict__ Wg,
    const float* __restrict__ bg, int T,
    int* __restrict__ counts, int* __restrict__ token_list,
    float* __restrict__ gate_list, unsigned short* __restrict__ xb)
{
    const int tid  = threadIdx.x;
    const int lane = tid & 63;
    const int wave = tid >> 6;
    const int tokBase = blockIdx.x * GATE_TOK;

    __shared__ float4 WgS[NUM_EXPERTS * 256];   // 32 KB: Wg[e][k], float4 units
    __shared__ double logitS[GATE_TOK][NUM_EXPERTS];
    __shared__ int cntS[NBUCKET];
    __shared__ int baseS[NBUCKET];

    if (tid < NBUCKET) cntS[tid] = 0;
#pragma unroll
    for (int i = 0; i < 8; i++)
        WgS[i * 256 + tid] = ((const float4*)Wg)[i * 256 + tid];
    __syncthreads();

    // Each wave handles 8 tokens; element k = q*256 + lane*4 + j.
    for (int tt = 0; tt < GATE_TOK / 4; tt++) {
        const int lt = wave * (GATE_TOK / 4) + tt;
        const int token = tokBase + lt;
        const float4* xr4 = (const float4*)(x + (size_t)token * D_MODEL);
        ushort4* xbr4 = (ushort4*)(xb + (size_t)token * D_MODEL);

        float4 xv[4];
#pragma unroll
        for (int q = 0; q < 4; q++) {
            float4 f = xr4[q * 64 + lane];
            xv[q] = f;
            ushort4 o;
            o.x = f32_to_bf16_rne(f.x);
            o.y = f32_to_bf16_rne(f.y);
            o.z = f32_to_bf16_rne(f.z);
            o.w = f32_to_bf16_rne(f.w);
            xbr4[q * 64 + lane] = o;
        }

        double acc[NUM_EXPERTS];
#pragma unroll
        for (int e = 0; e < NUM_EXPERTS; e++) {
            double a = 0.0;
#pragma unroll
            for (int q = 0; q < 4; q++) {
                float4 w = WgS[e * 256 + q * 64 + lane];
                a += (double)xv[q].x * (double)w.x;
                a += (double)xv[q].y * (double)w.y;
                a += (double)xv[q].z * (double)w.z;
                a += (double)xv[q].w * (double)w.w;
            }
            acc[e] = a;
        }
#pragma unroll
        for (int e = 0; e < NUM_EXPERTS; e++) {
            double a = acc[e];
            for (int off = 32; off > 0; off >>= 1) a += __shfl_xor(a, off, 64);
            acc[e] = a;
        }
        if (lane == 0) {
#pragma unroll
            for (int e = 0; e < NUM_EXPERTS; e++)
                logitS[lt][e] = acc[e] + (double)bg[e];
        }
    }
    __syncthreads();

    // Phase 2: one thread per token — top-2 + softmax + aggregated append.
    int i1 = 0, i2 = 0, o1 = 0, o2 = 0;
    double v1d = 0.0, v2d = 0.0;
    const int token2 = tokBase + tid;
    if (tid < GATE_TOK) {
        double lg[NUM_EXPERTS];
#pragma unroll
        for (int e = 0; e < NUM_EXPERTS; e++) lg[e] = logitS[tid][e];
        i1 = 0;
#pragma unroll
        for (int e = 1; e < NUM_EXPERTS; e++) if (lg[e] > lg[i1]) i1 = e;
        i2 = (i1 == 0) ? 1 : 0;
#pragma unroll
        for (int e = 0; e < NUM_EXPERTS; e++)
            if (e != i1 && lg[e] > lg[i2]) i2 = e;
        double m = lg[i1], den = 0.0;
#pragma unroll
        for (int e = 0; e < NUM_EXPERTS; e++) den += exp(lg[e] - m);
        v1d = exp(lg[i1] - m) / den;
        v2d = exp(lg[i2] - m) / den;
        o1 = atomicAdd(&cntS[i1], 1);          // primary bucket e
        o2 = atomicAdd(&cntS[8 + i2], 1);      // secondary bucket 8+e
    }
    __syncthreads();
    if (tid < NBUCKET) baseS[tid] = atomicAdd(&counts[tid], cntS[tid]);
    __syncthreads();
    if (tid < GATE_TOK) {
        int p1 = i1 * T + baseS[i1] + o1;
        token_list[p1] = token2;
        gate_list[p1]  = (float)v1d;
        int p2 = (8 + i2) * T + baseS[8 + i2] + o2;
        token_list[p2] = token2;
        gate_list[p2]  = (float)v2d;
    }
}

// ---------------------------------------------------------------------------
// fp32 -> bf16 converter (for We), float4-vectorized
// ---------------------------------------------------------------------------
__global__ __launch_bounds__(256) void convert_kernel(
    const float* __restrict__ src, unsigned short* __restrict__ dst, int n4)
{
    int i = blockIdx.x * 256 + threadIdx.x;
    if (i >= n4) return;
    float4 f = ((const float4*)src)[i];
    ushort4 o;
    o.x = f32_to_bf16_rne(f.x);
    o.y = f32_to_bf16_rne(f.y);
    o.z = f32_to_bf16_rne(f.z);
    o.w = f32_to_bf16_rne(f.w);
    ((ushort4*)dst)[i] = o;
}

// ---------------------------------------------------------------------------
// Per-bucket gathered GEMM over 16 virtual experts (slot = vexp>>3, weight
// e = vexp&7). Within a slot class each token appears exactly once, so the
// epilogue is plain bf16 stores into ybuf[slot][token][:] — NO atomics.
// LDS XOR-swizzled at 16B-chunk granularity (seg ^= row&7) to spread each
// ds_read_b128 uniformly over all 8 bank groups; the swizzle is applied on
// the staging SOURCE index so global_load_lds's wave-uniform dest is legal.
// ---------------------------------------------------------------------------
__global__ __launch_bounds__(256) void moe_gemm(
    const unsigned short* __restrict__ xb,   // [T][1024] bf16
    const unsigned short* __restrict__ wb,   // [E][1024][1024] bf16, K-contig
    const float* __restrict__ be,            // [E][1024]
    const int* __restrict__ counts,          // [16]
    const int* __restrict__ token_list,      // [16][T]
    const float* __restrict__ gate_list,     // [16][T]
    unsigned short* __restrict__ ybuf,       // [2][T][1024] bf16
    int T)
{
    const int bid = blockIdx.x;
    const int nt = bid & 7;
    const int rest = bid >> 3;
    const int vexp = rest & (NBUCKET - 1);
    const int mt = rest >> 4;
    const int e_w = vexp & 7;

    const int n_e = counts[vexp];
    const int m0 = mt * BM;
    if (m0 >= n_e) return;
    const int n0 = nt * BN;
    const int tid = threadIdx.x;

    __shared__ __align__(16) unsigned short As[BM * BK];
    __shared__ __align__(16) unsigned short Bs[BN * BK];
    __shared__ int   tokS[BM];
    __shared__ float gateS[BM];

    if (tid < BM) {
        int r = m0 + tid;
        int tk = 0; float gv = 0.f;
        if (r < n_e) {
            tk = token_list[vexp * T + r];
            gv = gate_list[vexp * T + r];
        }
        tokS[tid]  = tk;
        gateS[tid] = gv;
    }
    __syncthreads();

    // Staging sources, with XOR swizzle on the 16B segment index.
    const unsigned short* asrc[4];
    const unsigned short* bsrc[4];
    const unsigned short* wbase = wb + (size_t)e_w * D_MODEL * D_MODEL;
#pragma unroll
    for (int i = 0; i < 4; i++) {
        int flat = i * 256 + tid;
        int r = flat >> 3, seg = flat & 7;
        int ss = seg ^ (r & 7);
        asrc[i] = xb + (size_t)tokS[r] * D_MODEL + ss * 8;
        bsrc[i] = wbase + (size_t)(n0 + r) * D_MODEL + ss * 8;
    }

    const int wave = tid >> 6, lane = tid & 63;
    const int wm = (wave >> 1) * 64, wn = (wave & 1) * 64;
    const int frow = lane & 15;
    const int qq = lane >> 4;
    const int sw8 = frow & 7;

    f32x4 acc[4][4];
#pragma unroll
    for (int mi = 0; mi < 4; mi++)
#pragma unroll
        for (int ni = 0; ni < 4; ni++)
            acc[mi][ni] = (f32x4){0.f, 0.f, 0.f, 0.f};

    for (int kt = 0; kt < D_MODEL / BK; kt++) {
        const int k0 = kt * BK;
#pragma unroll
        for (int i = 0; i < 4; i++) {
            int flat = i * 256 + tid;
            gload_lds16(asrc[i] + k0, &As[flat * 8]);
            gload_lds16(bsrc[i] + k0, &Bs[flat * 8]);
        }
        __syncthreads();
#pragma unroll
        for (int ks = 0; ks < 2; ks++) {
            const int off = ((ks * 4 + qq) ^ sw8) * 8;   // swizzled k-offset (halfs)
            bf16x8 af[4], bfv[4];
#pragma unroll
            for (int mi = 0; mi < 4; mi++)
                af[mi] = *(const bf16x8*)&As[(wm + mi * 16 + frow) * BK + off];
#pragma unroll
            for (int ni = 0; ni < 4; ni++)
                bfv[ni] = *(const bf16x8*)&Bs[(wn + ni * 16 + frow) * BK + off];
#pragma unroll
            for (int mi = 0; mi < 4; mi++)
#pragma unroll
                for (int ni = 0; ni < 4; ni++)
                    acc[mi][ni] = __builtin_amdgcn_mfma_f32_16x16x32_bf16(
                        af[mi], bfv[ni], acc[mi][ni], 0, 0, 0);
        }
        __syncthreads();
    }

    // Epilogue: C/D layout col = lane&15, row = (lane>>4)*4 + reg.
    // Plain bf16 stores into this slot's per-token buffer — race-free.
    unsigned short* ybase = ybuf + (size_t)(vexp >> 3) * T * D_MODEL;
    const int rbase = (lane >> 4) * 4;
    const int col   = lane & 15;
#pragma unroll
    for (int mi = 0; mi < 4; mi++) {
#pragma unroll
        for (int r = 0; r < 4; r++) {
            int lrow = wm + mi * 16 + rbase + r;
            if (m0 + lrow < n_e) {
                int   tk = tokS[lrow];
                float gv = gateS[lrow];
                unsigned short* yr = ybase + (size_t)tk * D_MODEL;
#pragma unroll
                for (int ni = 0; ni < 4; ni++) {
                    int c = n0 + wn + ni * 16 + col;
                    float val = gv * (acc[mi][ni][r] + be[e_w * D_MODEL + c]);
                    yr[c] = f32_to_bf16_rne(val);
                }
            }
        }
    }
}

// ---------------------------------------------------------------------------
// Combine: out[t][d] = ybuf[0][t][d] + ybuf[1][t][d]  (bf16 -> fp32 add)
// ---------------------------------------------------------------------------
__global__ __launch_bounds__(256) void combine_kernel(
    const unsigned short* __restrict__ y0,
    const unsigned short* __restrict__ y1,
    float* __restrict__ out, int n4)
{
    int i = blockIdx.x * 256 + threadIdx.x;
    if (i >= n4) return;
    ushort4 a = ((const ushort4*)y0)[i];
    ushort4 b = ((const ushort4*)y1)[i];
    float4 o;
    o.x = bf16_to_f32(a.x) + bf16_to_f32(b.x);
    o.y = bf16_to_f32(a.y) + bf16_to_f32(b.y);
    o.z = bf16_to_f32(a.z) + bf16_to_f32(b.z);
    o.w = bf16_to_f32(a.w) + bf16_to_f32(b.w);
    ((float4*)out)[i] = o;
}

extern "C" void kernel_launch(void* const* d_in, const int* in_sizes, int n_in,
                              void* d_out, int out_size, void* d_ws, size_t ws_size,
                              hipStream_t stream) {
    const float* x  = (const float*)d_in[0];
    const float* Wg = (const float*)d_in[1];
    const float* bg = (const float*)d_in[2];
    const float* We = (const float*)d_in[3];
    const float* be = (const float*)d_in[4];
    // top_k (d_in[5]) is fixed at 2 per the reference; hard-coded.

    const int T = in_sizes[0] / D_MODEL;   // 8192 tokens

    // workspace carve-up (~68 MB total)
    char* ws = (char*)d_ws;
    unsigned short* xb = (unsigned short*)ws;                       // T*D bf16
    size_t off = (size_t)T * D_MODEL * 2;
    unsigned short* wbv = (unsigned short*)(ws + off);              // E*D*D bf16
    off += (size_t)NUM_EXPERTS * D_MODEL * D_MODEL * 2;
    int* counts = (int*)(ws + off);         off += 256;
    int* token_list = (int*)(ws + off);     off += (size_t)NBUCKET * T * 4;
    float* gate_list = (float*)(ws + off);  off += (size_t)NBUCKET * T * 4;
    unsigned short* ybuf = (unsigned short*)(ws + off);             // 2*T*D bf16
    off += (size_t)2 * T * D_MODEL * 2;

    hipMemsetAsync(counts, 0, 256, stream);

    int n4w = NUM_EXPERTS * D_MODEL * D_MODEL / 4;
    convert_kernel<<<(n4w + 255) / 256, 256, 0, stream>>>(We, wbv, n4w);

    gate_kernel<<<T / GATE_TOK, 256, 0, stream>>>(
        x, Wg, bg, T, counts, token_list, gate_list, xb);

    const int MT = (T + BM - 1) / BM;       // worst case: all tokens in one bucket
    moe_gemm<<<MT * NBUCKET * 8, 256, 0, stream>>>(
        xb, wbv, be, counts, token_list, gate_list, ybuf, T);

    int n4c = T * D_MODEL / 4;
    combine_kernel<<<(n4c + 255) / 256, 256, 0, stream>>>(
        ybuf, ybuf + (size_t)T * D_MODEL, (float*)d_out, n4c);
}